// Round 1
// baseline (503.212 us; speedup 1.0000x reference)
//
#include <hip/hip_runtime.h>
#include <cstdint>
#include <cstddef>

// TSPEdgeEmbedding on MI355X.
// Outputs (flat float32 in d_out, in reference return order):
//   [0, 2048000)              x = init_embeddings passthrough [B*n, D]
//   [2048000, 2848000)        edge_index row 0 (src), as float
//   [2848000, 3648000)        edge_index row 1 (dst), as float
//   [3648000, 106048000)      edge_emb [B*n*k, D] = dist*W + b
//
// One wave (64 lanes) per node. Lane l owns candidate neighbors
// j in [16l, 16l+16) (contiguous => ballot-lowest-lane == lowest-j tiebreak,
// matching lax.top_k / stable argsort semantics exactly).
// 50 sequential wave-min extractions with per-lane cached local argmin.

namespace {

constexpr int kB  = 16;
constexpr int kN  = 1000;
constexpr int kD  = 128;
constexpr int kK  = 50;
constexpr int kCPL = 16;                               // candidates per lane (64*16 = 1024 >= 1000)
constexpr int kNodesPerBlock = 4;                      // 4 waves / 256-thread block
constexpr int kBlocksPerBatch = kN / kNodesPerBlock;   // 250 (exact)

__global__ __launch_bounds__(256)
void tsp_edge_kernel(const float* __restrict__ locs,
                     const float* __restrict__ init_emb,
                     const float* __restrict__ W,
                     const float* __restrict__ bias,
                     float* __restrict__ out)
{
#pragma clang fp contract(off)   // match numpy: separate mul/add rounding, no FMA
  const int tid  = threadIdx.x;
  const int wave = tid >> 6;
  const int lane = tid & 63;
  const int blk  = blockIdx.x;
  const int b    = blk / kBlocksPerBatch;
  const int node_in_b = (blk % kBlocksPerBatch) * kNodesPerBlock + wave;
  const int node = b * kN + node_in_b;    // global node id (= src index)

  // ---- stage this batch's locs into LDS (shared by the 4 waves) ----
  __shared__ float2 sloc[kN];
  const float2* gl = reinterpret_cast<const float2*>(locs) + (size_t)b * kN;
  for (int t = tid; t < kN; t += 256) sloc[t] = gl[t];
  __syncthreads();

  const float2 my = sloc[node_in_b];

  // ---- per-lane candidate distances (registers) ----
  float d[kCPL];
  const int jbase = lane * kCPL;
#pragma unroll
  for (int s = 0; s < kCPL; ++s) {
    const int j = jbase + s;
    const bool valid = (j < kN) && (j != node_in_b);
    const float2 pj = sloc[(j < kN) ? j : 0];
    const float dx = my.x - pj.x;
    const float dy = my.y - pj.y;
    const float d2 = dx * dx + dy * dy;       // contract(off): matches np bitwise
    const float dd = sqrtf(d2 + 1e-12f);
    d[s] = valid ? dd : INFINITY;
  }

  // local argmin (strict < => earliest slot wins ties, i.e. lowest j)
  float best = d[0];
  int bslot = 0;
#pragma unroll
  for (int s = 1; s < kCPL; ++s) {
    if (d[s] < best) { best = d[s]; bslot = s; }
  }

  // ---- 50 sequential wave-min extractions ----
  float res_d = 0.0f;   // lane r (< kK) ends holding rank-r (dist, j)
  int   res_j = 0;
#pragma unroll 1
  for (int r = 0; r < kK; ++r) {
    float m = best;
#pragma unroll
    for (int off = 32; off >= 1; off >>= 1) m = fminf(m, __shfl_xor(m, off, 64));
    const unsigned long long msk = __ballot(best == m);
    const int owner = __ffsll(msk) - 1;          // lowest lane => lowest j on ties
    const int oslot = __shfl(bslot, owner, 64);
    const int jwin  = owner * kCPL + oslot;
    if (lane == r) { res_d = m; res_j = jwin; }
    if (lane == owner) {
      // invalidate extracted slot (unrolled cndmask chain, stays in VGPRs)
#pragma unroll
      for (int s = 0; s < kCPL; ++s) { if (s == oslot) d[s] = INFINITY; }
      best = d[0]; bslot = 0;
#pragma unroll
      for (int s = 1; s < kCPL; ++s) {
        if (d[s] < best) { best = d[s]; bslot = s; }
      }
    }
  }

  // ---- outputs ----
  constexpr size_t X_SZ    = (size_t)kB * kN * kD;   // 2,048,000
  constexpr size_t E_SZ    = (size_t)kB * kN * kK;   // 800,000
  constexpr size_t SRC_OFF = X_SZ;
  constexpr size_t DST_OFF = X_SZ + E_SZ;
  constexpr size_t EMB_OFF = X_SZ + 2 * E_SZ;

  // x passthrough: one row (128 floats) per wave, float2 per lane
  {
    const float2* srcp = reinterpret_cast<const float2*>(init_emb + (size_t)node * kD);
    float2* dstp = reinterpret_cast<float2*>(out + (size_t)node * kD);
    dstp[lane] = srcp[lane];
  }

  // edge_index (written as float values; max 15999 is exact in f32)
  if (lane < kK) {
    out[SRC_OFF + (size_t)node * kK + lane] = (float)node;
    out[DST_OFF + (size_t)node * kK + lane] = (float)(b * kN + res_j);
  }

  // edge_emb: 50 rows x 128 cols per wave. 32 lanes cover one row (float4 each),
  // so each iteration writes 2 rows; dist broadcast via shuffle from lane r0.
  const int colg = (lane & 31) * 4;
  const float4 wv = *reinterpret_cast<const float4*>(W + colg);
  const float4 bv = *reinterpret_cast<const float4*>(bias + colg);
  float* ebase = out + EMB_OFF + (size_t)node * (kK * kD);
#pragma unroll
  for (int rr = 0; rr < kK / 2; ++rr) {
    const int r0 = 2 * rr + (lane >> 5);
    const float a = __shfl(res_d, r0, 64);
    float4 v;
    v.x = a * wv.x + bv.x;
    v.y = a * wv.y + bv.y;
    v.z = a * wv.z + bv.z;
    v.w = a * wv.w + bv.w;
    *reinterpret_cast<float4*>(ebase + (size_t)r0 * kD + colg) = v;
  }
}

} // namespace

extern "C" void kernel_launch(void* const* d_in, const int* in_sizes, int n_in,
                              void* d_out, int out_size, void* d_ws, size_t ws_size,
                              hipStream_t stream) {
  const float* locs = (const float*)d_in[0];   // [16,1000,2]
  const float* emb  = (const float*)d_in[1];   // [16,1000,128]
  const float* W    = (const float*)d_in[2];   // [1,128]
  const float* bias = (const float*)d_in[3];   // [128]
  float* out = (float*)d_out;

  dim3 grid(kB * kBlocksPerBatch);   // 4000 blocks = 16000 waves = 1 per node
  dim3 block(256);
  hipLaunchKernelGGL(tsp_edge_kernel, grid, block, 0, stream, locs, emb, W, bias, out);
}